// Round 2
// baseline (9197.759 us; speedup 1.0000x reference)
//
#include <hip/hip_runtime.h>
#include <math.h>

// DNC forward, fp32. B=16 T=64 IN=256 H=512 M=256 W=64 R=4 IFACE=471.
// 13 graph nodes: memset, 7 transposes, xpart GEMM, LSTM barrier-chain kernel,
// out/xi wide GEMM, per-batch memory-module chain kernel, final y GEMM.

#define BZ    16
#define TZ    64
#define HID   512
#define NCELL 256
#define CSZ   64
#define NRD   4
#define G4H   2048
#define IFC   471
#define DEL   1e-6f

__device__ __forceinline__ float sig_(float x) { return 1.f / (1.f + expf(-x)); }
__device__ __forceinline__ float splus_(float x) { return fmaxf(x, 0.f) + log1pf(expf(-fabsf(x))); }

// ---------------------------------------------------------------- transpose
__global__ __launch_bounds__(256) void k_transpose(const float* __restrict__ src,
                                                   float* __restrict__ dst,
                                                   int rows, int cols, int kmax, int dst_stride) {
  __shared__ float tile[32][33];
  int c0 = blockIdx.x * 32, r0 = blockIdx.y * 32;
  int tx = threadIdx.x, ty = threadIdx.y;
  for (int i = ty; i < 32; i += 8) {
    int r = r0 + i, c = c0 + tx;
    tile[i][tx] = (r < rows && c < cols) ? src[(size_t)r * cols + c] : 0.f;
  }
  __syncthreads();
  for (int i = ty; i < 32; i += 8) {
    int c = c0 + i, r = r0 + tx;
    if (c < kmax && r < rows) dst[(size_t)c * dst_stride + r] = tile[tx][i];
  }
}

// ---------------------------------------------------------------- xpart GEMM
// xpart[tb][jg] = sum_k x[b][t][k] * Wih0T[k][jg] + bih0[jg] + bhh0[jg]
__global__ __launch_bounds__(256) void k_xpart(const float* __restrict__ x,
                                               const float* __restrict__ Wih0T,
                                               const float* __restrict__ bih0,
                                               const float* __restrict__ bhh0,
                                               float* __restrict__ xpart) {
  const int lane = threadIdx.x, ty = threadIdx.y;
  const int jg = blockIdx.x * 64 + lane;
  const int tb0 = blockIdx.y * 16;
  __shared__ float sx[16][256];
  const int tid = ty * 64 + lane;
  for (int idx = tid; idx < 16 * 256; idx += 256) {
    int row = idx >> 8, k = idx & 255;
    int tb = tb0 + row, tt = tb >> 4, bb = tb & 15;
    sx[row][k] = x[((size_t)bb * TZ + tt) * 256 + k];
  }
  __syncthreads();
  float acc[4] = {0.f, 0.f, 0.f, 0.f};
  for (int k = 0; k < 256; ++k) {
    float wv = Wih0T[(size_t)k * G4H + jg];
#pragma unroll
    for (int i = 0; i < 4; ++i) acc[i] = fmaf(wv, sx[ty * 4 + i][k], acc[i]);
  }
  float bias = bih0[jg] + bhh0[jg];
#pragma unroll
  for (int i = 0; i < 4; ++i)
    xpart[(size_t)(tb0 + ty * 4 + i) * G4H + jg] = acc[i] + bias;
}

// ---------------------------------------------------------------- LSTM chain
// 256 blocks: group0 (blocks 0..127) = cell0, group1 (128..255) = cell1.
// Phase p: group0 computes lstm0(t=p), group1 computes lstm1(t=p-1). One
// grid barrier per phase (flag tree: done[bid] stores + block0 aggregation).
__device__ __forceinline__ void gbar_flag(unsigned* done, unsigned* go,
                                          unsigned phase1, int bid, int tid) {
  __syncthreads();
  if (bid == 0) {
    if (tid == 0)
      __hip_atomic_store(&done[0], phase1, __ATOMIC_RELEASE, __HIP_MEMORY_SCOPE_AGENT);
    // 256 threads poll 256 block slots
    while (__hip_atomic_load(&done[tid], __ATOMIC_ACQUIRE, __HIP_MEMORY_SCOPE_AGENT) < phase1)
      __builtin_amdgcn_s_sleep(2);
    __syncthreads();
    if (tid == 0)
      __hip_atomic_store(go, phase1, __ATOMIC_RELEASE, __HIP_MEMORY_SCOPE_AGENT);
  } else {
    if (tid == 0) {
      __hip_atomic_store(&done[bid], phase1, __ATOMIC_RELEASE, __HIP_MEMORY_SCOPE_AGENT);
      while (__hip_atomic_load(go, __ATOMIC_ACQUIRE, __HIP_MEMORY_SCOPE_AGENT) < phase1)
        __builtin_amdgcn_s_sleep(2);
    }
    __syncthreads();
  }
}

__global__ __launch_bounds__(256, 1) void k_lstm_chain(
    const float* __restrict__ xpart,
    const float* __restrict__ Whh0T,
    const float* __restrict__ Wih1T, const float* __restrict__ Whh1T,
    const float* __restrict__ bih1, const float* __restrict__ bhh1,
    float* __restrict__ h0, float* __restrict__ c0,
    float* __restrict__ h1, float* __restrict__ c1,
    float* __restrict__ h1_all,
    unsigned* __restrict__ done, unsigned* __restrict__ go) {
  const int jl = threadIdx.x, ks = threadIdx.y;
  const int tid = ks * 64 + jl;
  const int bid = blockIdx.x;
  const int grp = bid >> 7;
  const int lb = bid & 127;
  const int b = lb >> 3, jb = lb & 7;  // bid%8 == jb -> same-jb blocks share XCD
  const int j = jb * 64 + jl;
  __shared__ float sh0[512], sh1[512];
  __shared__ float sred[4][4][64];

  for (int ph = 0; ph <= TZ; ++ph) {
    if (grp == 0 && ph < TZ) {
      const int t = ph, po = t & 1, pn = po ^ 1;
      const float* h0o = h0 + ((size_t)po * BZ + b) * HID;
      for (int k = tid; k < 512; k += 256) sh0[k] = h0o[k];
      __syncthreads();
      float a0 = 0.f, a1 = 0.f, a2 = 0.f, a3 = 0.f;
      const int kb = ks * 128;
#pragma unroll 4
      for (int k = kb; k < kb + 128; ++k) {
        const float hk = sh0[k];
        const float* wr = Whh0T + (size_t)k * G4H + j;
        a0 = fmaf(hk, wr[0], a0);
        a1 = fmaf(hk, wr[512], a1);
        a2 = fmaf(hk, wr[1024], a2);
        a3 = fmaf(hk, wr[1536], a3);
      }
      sred[ks][0][jl] = a0; sred[ks][1][jl] = a1; sred[ks][2][jl] = a2; sred[ks][3][jl] = a3;
      __syncthreads();
      if (ks == 0) {
        const float* xp = xpart + ((size_t)t * BZ + b) * G4H;
        float gi = sred[0][0][jl] + sred[1][0][jl] + sred[2][0][jl] + sred[3][0][jl] + xp[j];
        float gf = sred[0][1][jl] + sred[1][1][jl] + sred[2][1][jl] + sred[3][1][jl] + xp[512 + j];
        float gg = sred[0][2][jl] + sred[1][2][jl] + sred[2][2][jl] + sred[3][2][jl] + xp[1024 + j];
        float go_ = sred[0][3][jl] + sred[1][3][jl] + sred[2][3][jl] + sred[3][3][jl] + xp[1536 + j];
        gi = sig_(gi); gf = sig_(gf); go_ = sig_(go_); gg = tanhf(gg);
        float* cp = c0 + b * HID + j;
        float cc = gf * (*cp) + gi * gg;
        *cp = cc;
        h0[((size_t)pn * BZ + b) * HID + j] = go_ * tanhf(cc);
      }
    } else if (grp == 1 && ph >= 1) {
      const int t = ph - 1, po = t & 1, pn = po ^ 1;
      const float* h0n = h0 + ((size_t)pn * BZ + b) * HID;  // h0 produced at step t
      const float* h1o = h1 + ((size_t)po * BZ + b) * HID;
      for (int k = tid; k < 512; k += 256) { sh0[k] = h0n[k]; sh1[k] = h1o[k]; }
      __syncthreads();
      float a0 = 0.f, a1 = 0.f, a2 = 0.f, a3 = 0.f;
      const int kb = ks * 128;
#pragma unroll 2
      for (int k = kb; k < kb + 128; ++k) {
        const float x0 = sh0[k], x1 = sh1[k];
        const float* wi = Wih1T + (size_t)k * G4H + j;
        const float* wh = Whh1T + (size_t)k * G4H + j;
        a0 = fmaf(x0, wi[0], fmaf(x1, wh[0], a0));
        a1 = fmaf(x0, wi[512], fmaf(x1, wh[512], a1));
        a2 = fmaf(x0, wi[1024], fmaf(x1, wh[1024], a2));
        a3 = fmaf(x0, wi[1536], fmaf(x1, wh[1536], a3));
      }
      sred[ks][0][jl] = a0; sred[ks][1][jl] = a1; sred[ks][2][jl] = a2; sred[ks][3][jl] = a3;
      __syncthreads();
      if (ks == 0) {
        float gi = sred[0][0][jl] + sred[1][0][jl] + sred[2][0][jl] + sred[3][0][jl] + bih1[j] + bhh1[j];
        float gf = sred[0][1][jl] + sred[1][1][jl] + sred[2][1][jl] + sred[3][1][jl] + bih1[512 + j] + bhh1[512 + j];
        float gg = sred[0][2][jl] + sred[1][2][jl] + sred[2][2][jl] + sred[3][2][jl] + bih1[1024 + j] + bhh1[1024 + j];
        float go_ = sred[0][3][jl] + sred[1][3][jl] + sred[2][3][jl] + sred[3][3][jl] + bih1[1536 + j] + bhh1[1536 + j];
        gi = sig_(gi); gf = sig_(gf); go_ = sig_(go_); gg = tanhf(gg);
        float* cp = c1 + b * HID + j;
        float cc = gf * (*cp) + gi * gg;
        *cp = cc;
        float hv = go_ * tanhf(cc);
        h1[((size_t)pn * BZ + b) * HID + j] = hv;
        h1_all[((size_t)t * BZ + b) * HID + j] = hv;
      }
    }
    gbar_flag(done, go, (unsigned)(ph + 1), bid, tid);
  }
}

// ---------------------------------------------------------------- out/xi GEMM
// rows tb=0..1023; u<512 -> out_all[tb][u]; 512<=u<983 -> xi_all[tb][u-512]
__global__ __launch_bounds__(256) void k_xiout(const float* __restrict__ h1_all,
                                               const float* __restrict__ WoutT,
                                               const float* __restrict__ WifT,
                                               const float* __restrict__ bout,
                                               const float* __restrict__ bif,
                                               float* __restrict__ out_all,
                                               float* __restrict__ xi_all) {
  const int lane = threadIdx.x, ty = threadIdx.y;
  const int u = blockIdx.x * 64 + lane;
  const int row0 = blockIdx.y * 16;
  __shared__ float sh[16][512];
  const int tid = ty * 64 + lane;
  for (int idx = tid; idx < 16 * 512; idx += 256) {
    int r2 = idx >> 9, k = idx & 511;
    sh[r2][k] = h1_all[(size_t)(row0 + r2) * 512 + k];
  }
  __syncthreads();
  const bool isout = (u < 512);
  int uc = isout ? u : (u - 512);
  if (!isout && uc >= IFC) uc = 0;
  const float* wcol = isout ? (WoutT + u) : (WifT + uc);
  float bias = isout ? bout[u] : ((u - 512) < IFC ? bif[u - 512] : 0.f);
  float acc[4] = {0.f, 0.f, 0.f, 0.f};
  for (int k = 0; k < 512; ++k) {
    float wv = wcol[(size_t)k * 512];
#pragma unroll
    for (int i = 0; i < 4; ++i) acc[i] = fmaf(wv, sh[ty * 4 + i][k], acc[i]);
  }
#pragma unroll
  for (int i = 0; i < 4; ++i) {
    int row = row0 + ty * 4 + i;
    if (isout) out_all[(size_t)row * 512 + u] = acc[i] + bias;
    else if ((u - 512) < IFC) xi_all[(size_t)row * 512 + (u - 512)] = acc[i] + bias;
  }
}

// ---------------------------------------------------------------- memory module chain
// One block per batch, 1024 threads, loops t=0..63. State: rw/ww/usage/prec in
// LDS; mem[256][64] and link[256][256] in global (XCD-L2 resident).
__global__ __launch_bounds__(1024, 1) void k_memchain(const float* __restrict__ xi_all,
                                                      float* __restrict__ linkg,
                                                      float* __restrict__ memg,
                                                      float* __restrict__ rv_all) {
  const int b = blockIdx.x;
  const int tid = threadIdx.x;
  const int lane = tid & 63, wv = tid >> 6;  // 16 waves
  float* LNK = linkg + (size_t)b * (NCELL * NCELL);
  float* MEM = memg + (size_t)b * (NCELL * CSZ);

  __shared__ float sxi[512];
  __shared__ float srkn[256];
  __shared__ float swkn[64], sev[64], swvv[64];
  __shared__ float sscal[40];  // rs[4]@0, ws@4, fg[4]@8, ag@12, wg@13, wsum@14, rm[12]@20
  __shared__ float srw[4][256];
  __shared__ float sww[256], susage[256], sprec[256];
  __shared__ float ssim[4][256];  // sim -> cw in place
  __shared__ float sfwd[4][256];
  __shared__ float sa[256], sb_[256], sc_[256];
  __shared__ int srank[256];
  __shared__ float scr[5120];
  __shared__ float sred2[32];

  // init state
  for (int i = tid; i < 256; i += 1024) {
    sww[i] = 0.f; susage[i] = 0.f; sprec[i] = 0.f;
    srw[0][i] = 0.f; srw[1][i] = 0.f; srw[2][i] = 0.f; srw[3][i] = 0.f;
  }
  for (int i = tid; i < (NCELL * CSZ) / 4; i += 1024)
    ((float4*)MEM)[i] = make_float4(0.f, 0.f, 0.f, 0.f);
  for (int i = tid; i < (NCELL * NCELL) / 4; i += 1024)
    ((float4*)LNK)[i] = make_float4(0.f, 0.f, 0.f, 0.f);
  __syncthreads();

  for (int t = 0; t < TZ; ++t) {
    // ---- P0: load + parse xi ----
    if (tid < 512) sxi[tid] = xi_all[((size_t)t * BZ + b) * 512 + tid];
    __syncthreads();
    float rv = 0.f, wkv = 0.f;
    {
      if (tid < 256) rv = tanhf(sxi[tid]);
      float s2 = rv * rv;
#pragma unroll
      for (int off = 32; off; off >>= 1) s2 += __shfl_down(s2, off);
      if (tid < 256 && lane == 0) sred2[wv] = 1.f / (sqrtf(s2) + DEL);
      if (wv == 4) {
        wkv = tanhf(sxi[260 + lane]);
        float w2 = wkv * wkv;
#pragma unroll
        for (int off = 32; off; off >>= 1) w2 += __shfl_down(w2, off);
        if (lane == 0) sred2[4] = 1.f / (sqrtf(w2) + DEL);
      }
      if (wv == 5) sev[lane] = sig_(sxi[325 + lane]);
      if (wv == 6) swvv[lane] = tanhf(sxi[389 + lane]);
      if (wv == 7) {
        if (lane < 4) sscal[lane] = splus_(sxi[256 + lane]);
        if (lane == 4) sscal[4] = splus_(sxi[324]);
        if (lane >= 8 && lane < 12) sscal[lane] = sig_(sxi[453 + (lane - 8)]);
        if (lane == 12) sscal[12] = sig_(sxi[457]);
        if (lane == 13) sscal[13] = sig_(sxi[458]);
        if (lane >= 16 && lane < 20) {
          int r = lane - 16;
          float a = sxi[459 + r * 3], b2 = sxi[460 + r * 3], c2 = sxi[461 + r * 3];
          float mx3 = fmaxf(a, fmaxf(b2, c2));
          float ea = expf(a - mx3), eb = expf(b2 - mx3), ec = expf(c2 - mx3);
          float iv = 1.f / (ea + eb + ec);
          sscal[20 + r * 3 + 0] = ea * iv;
          sscal[20 + r * 3 + 1] = eb * iv;
          sscal[20 + r * 3 + 2] = ec * iv;
        }
      }
    }
    __syncthreads();
    if (tid < 256) srkn[tid] = rv * sred2[wv];
    if (wv == 4) swkn[lane] = wkv * sred2[4];
    __syncthreads();

    // ---- P1: usage update + write-content weights (old mem) ----
    float un_r = 0.f;
    if (tid < 256) {
      float wwo = sww[tid], uo = susage[tid];
      float u1 = uo + (1.f - uo) * wwo;
      float psi = 1.f;
#pragma unroll
      for (int r = 0; r < 4; ++r) psi *= 1.f - sscal[8 + r] * srw[r][tid];
      un_r = u1 * psi;
      susage[tid] = un_r;
    }
    {
      int m = tid >> 2, q = tid & 3;
      const float4* mrow = (const float4*)(MEM + m * 64 + q * 16);
      float dot = 0.f, nn = 0.f;
#pragma unroll
      for (int i = 0; i < 4; ++i) {
        float4 v = mrow[i];
        int w0 = q * 16 + i * 4;
        dot += v.x * swkn[w0] + v.y * swkn[w0 + 1] + v.z * swkn[w0 + 2] + v.w * swkn[w0 + 3];
        nn += v.x * v.x + v.y * v.y + v.z * v.z + v.w * v.w;
      }
      scr[(m * 4 + q) * 2 + 0] = dot;
      scr[(m * 4 + q) * 2 + 1] = nn;
    }
    __syncthreads();
    float simv = 0.f;
    if (tid < 256) {
      int base = tid * 8;
      float dot = scr[base] + scr[base + 2] + scr[base + 4] + scr[base + 6];
      float nn = scr[base + 1] + scr[base + 3] + scr[base + 5] + scr[base + 7];
      simv = sscal[4] * dot / (sqrtf(nn) + DEL);
    }
    {
      float mx = simv;
#pragma unroll
      for (int off = 32; off; off >>= 1) mx = fmaxf(mx, __shfl_xor(mx, off));
      if (tid < 256 && lane == 0) sred2[wv] = mx;
    }
    __syncthreads();
    float wcw_r = 0.f;
    {
      float mx = fmaxf(fmaxf(sred2[0], sred2[1]), fmaxf(sred2[2], sred2[3]));
      float e = (tid < 256) ? expf(simv - mx) : 0.f;
      float s = e;
#pragma unroll
      for (int off = 32; off; off >>= 1) s += __shfl_xor(s, off);
      if (tid < 256 && lane == 0) sred2[16 + wv] = s;
      __syncthreads();
      float sm = sred2[16] + sred2[17] + sred2[18] + sred2[19];
      wcw_r = e / sm;
    }

    // ---- P2: allocation (stable rank + exclusive cumprod) ----
    if (tid < 256) sa[tid] = DEL + (1.f - DEL) * un_r;
    __syncthreads();
    {
      int m = tid & 255, seg = tid >> 8;
      float um = sa[m];
      int cnt = 0;
      for (int j2 = seg * 64; j2 < seg * 64 + 64; ++j2) {
        float uj = sa[j2];
        cnt += (uj < um || (uj == um && j2 < m)) ? 1 : 0;
      }
      ((int*)scr)[seg * 256 + m] = cnt;
    }
    __syncthreads();
    if (tid < 256) {
      int rank = ((int*)scr)[tid] + ((int*)scr)[256 + tid] + ((int*)scr)[512 + tid] + ((int*)scr)[768 + tid];
      sb_[rank] = sa[tid];
      srank[tid] = rank;
    }
    __syncthreads();
    float inc = 0.f;
    if (tid < 256) {
      inc = sb_[tid];
#pragma unroll
      for (int off = 1; off < 64; off <<= 1) {
        float pp = __shfl_up(inc, off);
        if (lane >= off) inc *= pp;
      }
      if (lane == 63) sred2[8 + wv] = inc;
    }
    __syncthreads();
    if (tid < 256) {
      float pref = 1.f;
      for (int w2 = 0; w2 < wv; ++w2) pref *= sred2[8 + w2];
      float excl = __shfl_up(inc, 1);
      if (lane == 0) excl = 1.f;
      sc_[tid] = excl * pref;
    }
    __syncthreads();

    // ---- P3: write weighting + wsum ----
    if (tid < 256) {
      float alo = (1.f - sa[tid]) * sc_[srank[tid]];
      float wwn = sscal[13] * (sscal[12] * alo + (1.f - sscal[12]) * wcw_r);
      sww[tid] = wwn;
      float s = wwn;
#pragma unroll
      for (int off = 32; off; off >>= 1) s += __shfl_xor(s, off);
      if (lane == 0) sred2[wv] = s;
    }
    __syncthreads();
    if (tid == 0) sscal[14] = sred2[0] + sred2[1] + sred2[2] + sred2[3];
    __syncthreads();

    // ---- P4: memory erase/write + read-content sims ----
    {
      int m = tid >> 2, q = tid & 3;
      float wm = sww[m];
      float4* mrow = (float4*)(MEM + m * 64 + q * 16);
      float nn = 0.f, d0 = 0.f, d1 = 0.f, d2 = 0.f, d3 = 0.f;
#pragma unroll
      for (int i = 0; i < 4; ++i) {
        float4 v = mrow[i];
        int w0 = q * 16 + i * 4;
        v.x = v.x * (1.f - wm * sev[w0 + 0]) + wm * swvv[w0 + 0];
        v.y = v.y * (1.f - wm * sev[w0 + 1]) + wm * swvv[w0 + 1];
        v.z = v.z * (1.f - wm * sev[w0 + 2]) + wm * swvv[w0 + 2];
        v.w = v.w * (1.f - wm * sev[w0 + 3]) + wm * swvv[w0 + 3];
        mrow[i] = v;
        nn += v.x * v.x + v.y * v.y + v.z * v.z + v.w * v.w;
        d0 += v.x * srkn[w0] + v.y * srkn[w0 + 1] + v.z * srkn[w0 + 2] + v.w * srkn[w0 + 3];
        d1 += v.x * srkn[64 + w0] + v.y * srkn[64 + w0 + 1] + v.z * srkn[64 + w0 + 2] + v.w * srkn[64 + w0 + 3];
        d2 += v.x * srkn[128 + w0] + v.y * srkn[128 + w0 + 1] + v.z * srkn[128 + w0 + 2] + v.w * srkn[128 + w0 + 3];
        d3 += v.x * srkn[192 + w0] + v.y * srkn[192 + w0 + 1] + v.z * srkn[192 + w0 + 2] + v.w * srkn[192 + w0 + 3];
      }
      int base = (m * 4 + q) * 5;
      scr[base] = nn; scr[base + 1] = d0; scr[base + 2] = d1; scr[base + 3] = d2; scr[base + 4] = d3;
    }
    __syncthreads();
    if (tid < 256) {
      int base = tid * 20;
      float nn = scr[base] + scr[base + 5] + scr[base + 10] + scr[base + 15];
      float invn = 1.f / (sqrtf(nn) + DEL);
#pragma unroll
      for (int r = 0; r < 4; ++r) {
        float d = scr[base + 1 + r] + scr[base + 6 + r] + scr[base + 11 + r] + scr[base + 16 + r];
        ssim[r][tid] = sscal[r] * d * invn;
      }
    }
    __syncthreads();
    // per-head softmax over 256 cells (head = tid>>8)
    {
      int r = tid >> 8, m = tid & 255;
      float v = ssim[r][m];
      float mx = v;
#pragma unroll
      for (int off = 32; off; off >>= 1) mx = fmaxf(mx, __shfl_xor(mx, off));
      if (lane == 0) sred2[wv] = mx;
      __syncthreads();
      mx = fmaxf(fmaxf(sred2[r * 4], sred2[r * 4 + 1]), fmaxf(sred2[r * 4 + 2], sred2[r * 4 + 3]));
      float e = expf(v - mx);
      float s = e;
#pragma unroll
      for (int off = 32; off; off >>= 1) s += __shfl_xor(s, off);
      if (lane == 0) sred2[16 + wv] = s;
      __syncthreads();
      s = sred2[16 + r * 4] + sred2[16 + r * 4 + 1] + sred2[16 + r * 4 + 2] + sred2[16 + r * 4 + 3];
      ssim[r][m] = e / s;  // now cw
    }
    __syncthreads();

    // ---- P5: link row update + fwd partials ----
    {
      int m = tid >> 2, q = tid & 3;
      float wm = sww[m];
      float4* lrow = (float4*)(LNK + m * 256 + q * 64);
      float f0 = 0.f, f1 = 0.f, f2 = 0.f, f3 = 0.f;
#pragma unroll 4
      for (int i = 0; i < 16; ++i) {
        int n0 = q * 64 + i * 4;
        float4 lv = lrow[i];
        float4 wc = *(const float4*)&sww[n0];
        float4 pc = *(const float4*)&sprec[n0];
        lv.x = (n0 + 0 == m) ? 0.f : (1.f - wm - wc.x) * lv.x + wm * pc.x;
        lv.y = (n0 + 1 == m) ? 0.f : (1.f - wm - wc.y) * lv.y + wm * pc.y;
        lv.z = (n0 + 2 == m) ? 0.f : (1.f - wm - wc.z) * lv.z + wm * pc.z;
        lv.w = (n0 + 3 == m) ? 0.f : (1.f - wm - wc.w) * lv.w + wm * pc.w;
        lrow[i] = lv;
        float4 r0v = *(const float4*)&srw[0][n0];
        float4 r1v = *(const float4*)&srw[1][n0];
        float4 r2v = *(const float4*)&srw[2][n0];
        float4 r3v = *(const float4*)&srw[3][n0];
        f0 += lv.x * r0v.x + lv.y * r0v.y + lv.z * r0v.z + lv.w * r0v.w;
        f1 += lv.x * r1v.x + lv.y * r1v.y + lv.z * r1v.z + lv.w * r1v.w;
        f2 += lv.x * r2v.x + lv.y * r2v.y + lv.z * r2v.z + lv.w * r2v.w;
        f3 += lv.x * r3v.x + lv.y * r3v.y + lv.z * r3v.z + lv.w * r3v.w;
      }
      int base = (m * 4 + q) * 4;
      scr[base] = f0; scr[base + 1] = f1; scr[base + 2] = f2; scr[base + 3] = f3;
    }
    __syncthreads();
    if (tid < 256) {
      int base = tid * 16;
#pragma unroll
      for (int r = 0; r < 4; ++r)
        sfwd[r][tid] = scr[base + r] + scr[base + 4 + r] + scr[base + 8 + r] + scr[base + 12 + r];
    }
    __syncthreads();

    // ---- P6: bwd column pass ----
    {
      int n = tid & 255, seg = tid >> 8;
      float b0 = 0.f, b1 = 0.f, b2 = 0.f, b3 = 0.f;
      for (int m2 = seg * 64; m2 < seg * 64 + 64; ++m2) {
        float lv = LNK[m2 * 256 + n];
        b0 = fmaf(srw[0][m2], lv, b0);
        b1 = fmaf(srw[1][m2], lv, b1);
        b2 = fmaf(srw[2][m2], lv, b2);
        b3 = fmaf(srw[3][m2], lv, b3);
      }
      int base = (n * 4 + seg) * 4;
      scr[base] = b0; scr[base + 1] = b1; scr[base + 2] = b2; scr[base + 3] = b3;
    }
    __syncthreads();

    // ---- P7: rw update + precedence ----
    {
      int r = tid >> 8, m = tid & 255;
      int base = m * 16;
      float bwd = scr[base + r] + scr[base + 4 + r] + scr[base + 8 + r] + scr[base + 12 + r];
      float rwn = sscal[20 + r * 3 + 0] * bwd + sscal[20 + r * 3 + 1] * sfwd[r][m] +
                  sscal[20 + r * 3 + 2] * ssim[r][m];
      srw[r][m] = rwn;
    }
    if (tid < 256) sprec[tid] = (1.f - sscal[14]) * sprec[tid] + sww[tid];
    __syncthreads();

    // ---- P8: read vectors ----
    {
      int r = tid >> 8, seg = (tid >> 6) & 3, w = lane;
      float acc = 0.f;
      for (int m2 = seg * 64; m2 < seg * 64 + 64; ++m2)
        acc = fmaf(srw[r][m2], MEM[m2 * 64 + w], acc);
      scr[(r * 64 + w) * 4 + seg] = acc;
    }
    __syncthreads();
    if (tid < 256)
      rv_all[((size_t)t * BZ + b) * 256 + tid] =
          scr[tid * 4] + scr[tid * 4 + 1] + scr[tid * 4 + 2] + scr[tid * 4 + 3];
    __syncthreads();
  }
}

// ---------------------------------------------------------------- final y GEMM
__global__ __launch_bounds__(256) void k_y(const float* __restrict__ out_all,
                                           const float* __restrict__ rv_all,
                                           const float* __restrict__ WmemT,
                                           const float* __restrict__ bmem,
                                           float* __restrict__ y) {
  const int lane = threadIdx.x, ty = threadIdx.y;
  const int o = blockIdx.x * 64 + lane;
  const int tb0 = blockIdx.y * 16;
  __shared__ float sin_[16][768];
  const int tid = ty * 64 + lane;
  for (int idx = tid; idx < 16 * 768; idx += 256) {
    int row = idx / 768, k = idx % 768;
    int tb = tb0 + row;
    sin_[row][k] = (k < 512) ? out_all[(size_t)tb * HID + k]
                             : rv_all[(size_t)tb * 256 + (k - 512)];
  }
  __syncthreads();
  float acc[4] = {0.f, 0.f, 0.f, 0.f};
  for (int k = 0; k < 768; ++k) {
    float wv = WmemT[(size_t)k * 256 + o];
#pragma unroll
    for (int i = 0; i < 4; ++i) acc[i] = fmaf(wv, sin_[ty * 4 + i][k], acc[i]);
  }
  float bo = bmem[o];
#pragma unroll
  for (int i = 0; i < 4; ++i) {
    int tb = tb0 + ty * 4 + i;
    int tt = tb >> 4, bb = tb & 15;
    y[((size_t)bb * TZ + tt) * 256 + o] = acc[i] + bo;
  }
}

extern "C" void kernel_launch(void* const* d_in, const int* in_sizes, int n_in,
                              void* d_out, int out_size, void* d_ws, size_t ws_size,
                              hipStream_t stream) {
  (void)in_sizes; (void)n_in; (void)out_size; (void)ws_size;
  const float* x    = (const float*)d_in[0];
  const float* Wih0 = (const float*)d_in[1];
  const float* bih0 = (const float*)d_in[2];
  const float* Whh0 = (const float*)d_in[3];
  const float* bhh0 = (const float*)d_in[4];
  const float* Wih1 = (const float*)d_in[5];
  const float* bih1 = (const float*)d_in[6];
  const float* Whh1 = (const float*)d_in[7];
  const float* bhh1 = (const float*)d_in[8];
  const float* Wout = (const float*)d_in[9];
  const float* bout = (const float*)d_in[10];
  const float* Wif  = (const float*)d_in[11];
  const float* bif  = (const float*)d_in[12];
  const float* Wmem = (const float*)d_in[13];
  const float* bmem = (const float*)d_in[14];
  float* y = (float*)d_out;

  float* p = (float*)d_ws;
  auto take = [&](size_t n) { float* q = p; p += n; return q; };
  float* Wih0T   = take((size_t)256 * 2048);
  float* Whh0T   = take((size_t)512 * 2048);
  float* Wih1T   = take((size_t)512 * 2048);
  float* Whh1T   = take((size_t)512 * 2048);
  float* WoutT   = take((size_t)512 * 512);
  float* WifT    = take((size_t)512 * 512);
  float* WmemT   = take((size_t)768 * 256);
  float* xpart   = take((size_t)TZ * BZ * G4H);
  float* h1_all  = take((size_t)TZ * BZ * HID);
  float* out_all = take((size_t)TZ * BZ * HID);
  float* xi_all  = take((size_t)TZ * BZ * 512);
  float* rv_all  = take((size_t)TZ * BZ * 256);
  float* linkg   = take((size_t)BZ * NCELL * NCELL);
  float* memg    = take((size_t)BZ * NCELL * CSZ);
  float* zstart  = p;
  float* h0      = take((size_t)2 * BZ * HID);
  float* c0      = take((size_t)BZ * HID);
  float* h1      = take((size_t)2 * BZ * HID);
  float* c1      = take((size_t)BZ * HID);
  float* syncf   = take((size_t)512);
  size_t zbytes = (size_t)((char*)p - (char*)zstart);
  unsigned* done = (unsigned*)syncf;
  unsigned* go   = done + 256;

  hipMemsetAsync(zstart, 0, zbytes, stream);

  dim3 tb32(32, 8);
  hipLaunchKernelGGL(k_transpose, dim3(8, 64), tb32, 0, stream, Wih0, Wih0T, 2048, 512, 256, 2048);
  hipLaunchKernelGGL(k_transpose, dim3(16, 64), tb32, 0, stream, Whh0, Whh0T, 2048, 512, 512, 2048);
  hipLaunchKernelGGL(k_transpose, dim3(16, 64), tb32, 0, stream, Wih1, Wih1T, 2048, 512, 512, 2048);
  hipLaunchKernelGGL(k_transpose, dim3(16, 64), tb32, 0, stream, Whh1, Whh1T, 2048, 512, 512, 2048);
  hipLaunchKernelGGL(k_transpose, dim3(16, 16), tb32, 0, stream, Wout, WoutT, 512, 512, 512, 512);
  hipLaunchKernelGGL(k_transpose, dim3(16, 15), tb32, 0, stream, Wif, WifT, 471, 512, 512, 512);
  hipLaunchKernelGGL(k_transpose, dim3(24, 8), tb32, 0, stream, Wmem, WmemT, 256, 768, 768, 256);

  hipLaunchKernelGGL(k_xpart, dim3(32, 64), dim3(64, 4), 0, stream, x, Wih0T, bih0, bhh0, xpart);

  hipLaunchKernelGGL(k_lstm_chain, dim3(256), dim3(64, 4), 0, stream,
                     xpart, Whh0T, Wih1T, Whh1T, bih1, bhh1,
                     h0, c0, h1, c1, h1_all, done, go);

  hipLaunchKernelGGL(k_xiout, dim3(16, 64), dim3(64, 4), 0, stream,
                     h1_all, WoutT, WifT, bout, bif, out_all, xi_all);

  hipLaunchKernelGGL(k_memchain, dim3(16), dim3(1024), 0, stream,
                     xi_all, linkg, memg, rv_all);

  hipLaunchKernelGGL(k_y, dim3(4, 64), dim3(64, 4), 0, stream, out_all, rv_all, WmemT, bmem, y);
}

// Round 3
// 4559.407 us; speedup vs baseline: 2.0173x; 2.0173x over previous
//
#include <hip/hip_runtime.h>
#include <math.h>

// DNC forward, fp32. B=16 T=64 IN=256 H=512 M=256 W=64 R=4 IFACE=471.
// Structure: memset + 7 transposes + xpart GEMM + 65 pipelined LSTM step
// dispatches + out/xi GEMM + persistent per-batch memory-module kernel
// (conflict-free LDS layouts) + final y GEMM.  ~77 graph nodes.

#define BZ    16
#define TZ    64
#define HID   512
#define NCELL 256
#define CSZ   64
#define NRD   4
#define G4H   2048
#define IFC   471
#define DEL   1e-6f
#define SMT   257   // LDS mem^T row stride (64 rows of 256 + pad)

__device__ __forceinline__ float sig_(float x) { return 1.f / (1.f + expf(-x)); }
__device__ __forceinline__ float splus_(float x) { return fmaxf(x, 0.f) + log1pf(expf(-fabsf(x))); }

// ---------------------------------------------------------------- transpose
__global__ __launch_bounds__(256) void k_transpose(const float* __restrict__ src,
                                                   float* __restrict__ dst,
                                                   int rows, int cols, int kmax, int dst_stride) {
  __shared__ float tile[32][33];
  int c0 = blockIdx.x * 32, r0 = blockIdx.y * 32;
  int tx = threadIdx.x, ty = threadIdx.y;
  for (int i = ty; i < 32; i += 8) {
    int r = r0 + i, c = c0 + tx;
    tile[i][tx] = (r < rows && c < cols) ? src[(size_t)r * cols + c] : 0.f;
  }
  __syncthreads();
  for (int i = ty; i < 32; i += 8) {
    int c = c0 + i, r = r0 + tx;
    if (c < kmax && r < rows) dst[(size_t)c * dst_stride + r] = tile[tx][i];
  }
}

// ---------------------------------------------------------------- xpart GEMM
__global__ __launch_bounds__(256) void k_xpart(const float* __restrict__ x,
                                               const float* __restrict__ Wih0T,
                                               const float* __restrict__ bih0,
                                               const float* __restrict__ bhh0,
                                               float* __restrict__ xpart) {
  const int lane = threadIdx.x, ty = threadIdx.y;
  const int jg = blockIdx.x * 64 + lane;
  const int tb0 = blockIdx.y * 16;
  __shared__ float sx[16][256];
  const int tid = ty * 64 + lane;
  for (int idx = tid; idx < 16 * 256; idx += 256) {
    int row = idx >> 8, k = idx & 255;
    int tb = tb0 + row, tt = tb >> 4, bb = tb & 15;
    sx[row][k] = x[((size_t)bb * TZ + tt) * 256 + k];
  }
  __syncthreads();
  float acc[4] = {0.f, 0.f, 0.f, 0.f};
  for (int k = 0; k < 256; ++k) {
    float wv = Wih0T[(size_t)k * G4H + jg];
#pragma unroll
    for (int i = 0; i < 4; ++i) acc[i] = fmaf(wv, sx[ty * 4 + i][k], acc[i]);
  }
  float bias = bih0[jg] + bhh0[jg];
#pragma unroll
  for (int i = 0; i < 4; ++i)
    xpart[(size_t)(tb0 + ty * 4 + i) * G4H + jg] = acc[i] + bias;
}

// ---------------------------------------------------------------- LSTM step (pipelined)
// dispatch ph: blocks 0..127 compute cell0 at t=ph; blocks 128..255 compute
// cell1 at t=ph-1 (uses h0 produced by the PREVIOUS dispatch -> no race).
__global__ __launch_bounds__(256) void k_lstm_step(
    const float* __restrict__ xpart,
    const float* __restrict__ Whh0T,
    const float* __restrict__ Wih1T, const float* __restrict__ Whh1T,
    const float* __restrict__ bih1, const float* __restrict__ bhh1,
    float* __restrict__ h0, float* __restrict__ c0,
    float* __restrict__ h1, float* __restrict__ c1,
    float* __restrict__ h1_all, int ph) {
  const int jl = threadIdx.x, ks = threadIdx.y;
  const int tid = ks * 64 + jl;
  const int bid = blockIdx.x;
  const int grp = bid >> 7;
  const int lb = bid & 127;
  const int b = lb >> 3, jb = lb & 7;
  const int j = jb * 64 + jl;
  __shared__ float sh0[512], sh1[512];
  __shared__ float sred[4][4][64];

  if (grp == 0) {
    if (ph >= TZ) return;
    const int t = ph, po = t & 1, pn = po ^ 1;
    const float* h0o = h0 + ((size_t)po * BZ + b) * HID;
    for (int k = tid; k < 512; k += 256) sh0[k] = h0o[k];
    __syncthreads();
    float a0 = 0.f, a1 = 0.f, a2 = 0.f, a3 = 0.f;
    const int kb = ks * 128;
#pragma unroll 8
    for (int k = kb; k < kb + 128; ++k) {
      const float hk = sh0[k];
      const float* wr = Whh0T + (size_t)k * G4H + j;
      a0 = fmaf(hk, wr[0], a0);
      a1 = fmaf(hk, wr[512], a1);
      a2 = fmaf(hk, wr[1024], a2);
      a3 = fmaf(hk, wr[1536], a3);
    }
    sred[ks][0][jl] = a0; sred[ks][1][jl] = a1; sred[ks][2][jl] = a2; sred[ks][3][jl] = a3;
    __syncthreads();
    if (ks == 0) {
      const float* xp = xpart + ((size_t)t * BZ + b) * G4H;
      float gi = sred[0][0][jl] + sred[1][0][jl] + sred[2][0][jl] + sred[3][0][jl] + xp[j];
      float gf = sred[0][1][jl] + sred[1][1][jl] + sred[2][1][jl] + sred[3][1][jl] + xp[512 + j];
      float gg = sred[0][2][jl] + sred[1][2][jl] + sred[2][2][jl] + sred[3][2][jl] + xp[1024 + j];
      float go_ = sred[0][3][jl] + sred[1][3][jl] + sred[2][3][jl] + sred[3][3][jl] + xp[1536 + j];
      gi = sig_(gi); gf = sig_(gf); go_ = sig_(go_); gg = tanhf(gg);
      float* cp = c0 + b * HID + j;
      float cc = gf * (*cp) + gi * gg;
      *cp = cc;
      h0[((size_t)pn * BZ + b) * HID + j] = go_ * tanhf(cc);
    }
  } else {
    if (ph < 1) return;
    const int t = ph - 1, po = t & 1, pn = po ^ 1;
    const float* h0n = h0 + ((size_t)pn * BZ + b) * HID;  // produced at step t
    const float* h1o = h1 + ((size_t)po * BZ + b) * HID;
    for (int k = tid; k < 512; k += 256) { sh0[k] = h0n[k]; sh1[k] = h1o[k]; }
    __syncthreads();
    float a0 = 0.f, a1 = 0.f, a2 = 0.f, a3 = 0.f;
    const int kb = ks * 128;
#pragma unroll 4
    for (int k = kb; k < kb + 128; ++k) {
      const float x0 = sh0[k], x1 = sh1[k];
      const float* wi = Wih1T + (size_t)k * G4H + j;
      const float* wh = Whh1T + (size_t)k * G4H + j;
      a0 = fmaf(x0, wi[0], fmaf(x1, wh[0], a0));
      a1 = fmaf(x0, wi[512], fmaf(x1, wh[512], a1));
      a2 = fmaf(x0, wi[1024], fmaf(x1, wh[1024], a2));
      a3 = fmaf(x0, wi[1536], fmaf(x1, wh[1536], a3));
    }
    sred[ks][0][jl] = a0; sred[ks][1][jl] = a1; sred[ks][2][jl] = a2; sred[ks][3][jl] = a3;
    __syncthreads();
    if (ks == 0) {
      float gi = sred[0][0][jl] + sred[1][0][jl] + sred[2][0][jl] + sred[3][0][jl] + bih1[j] + bhh1[j];
      float gf = sred[0][1][jl] + sred[1][1][jl] + sred[2][1][jl] + sred[3][1][jl] + bih1[512 + j] + bhh1[512 + j];
      float gg = sred[0][2][jl] + sred[1][2][jl] + sred[2][2][jl] + sred[3][2][jl] + bih1[1024 + j] + bhh1[1024 + j];
      float go_ = sred[0][3][jl] + sred[1][3][jl] + sred[2][3][jl] + sred[3][3][jl] + bih1[1536 + j] + bhh1[1536 + j];
      gi = sig_(gi); gf = sig_(gf); go_ = sig_(go_); gg = tanhf(gg);
      float* cp = c1 + b * HID + j;
      float cc = gf * (*cp) + gi * gg;
      *cp = cc;
      float hv = go_ * tanhf(cc);
      h1[((size_t)pn * BZ + b) * HID + j] = hv;
      h1_all[((size_t)t * BZ + b) * HID + j] = hv;
    }
  }
}

// ---------------------------------------------------------------- out/xi GEMM
__global__ __launch_bounds__(256) void k_xiout(const float* __restrict__ h1_all,
                                               const float* __restrict__ WoutT,
                                               const float* __restrict__ WifT,
                                               const float* __restrict__ bout,
                                               const float* __restrict__ bif,
                                               float* __restrict__ out_all,
                                               float* __restrict__ xi_all) {
  const int lane = threadIdx.x, ty = threadIdx.y;
  const int u = blockIdx.x * 64 + lane;
  const int row0 = blockIdx.y * 16;
  __shared__ float sh[16][512];
  const int tid = ty * 64 + lane;
  for (int idx = tid; idx < 16 * 512; idx += 256) {
    int r2 = idx >> 9, k = idx & 511;
    sh[r2][k] = h1_all[(size_t)(row0 + r2) * 512 + k];
  }
  __syncthreads();
  const bool isout = (u < 512);
  int uc = isout ? u : (u - 512);
  if (!isout && uc >= IFC) uc = 0;
  const float* wcol = isout ? (WoutT + u) : (WifT + uc);
  float bias = isout ? bout[u] : ((u - 512) < IFC ? bif[u - 512] : 0.f);
  float acc[4] = {0.f, 0.f, 0.f, 0.f};
  for (int k = 0; k < 512; ++k) {
    float wv = wcol[(size_t)k * 512];
#pragma unroll
    for (int i = 0; i < 4; ++i) acc[i] = fmaf(wv, sh[ty * 4 + i][k], acc[i]);
  }
#pragma unroll
  for (int i = 0; i < 4; ++i) {
    int row = row0 + ty * 4 + i;
    if (isout) out_all[(size_t)row * 512 + u] = acc[i] + bias;
    else if ((u - 512) < IFC) xi_all[(size_t)row * 512 + (u - 512)] = acc[i] + bias;
  }
}

// ---------------------------------------------------------------- memory module chain
// One 1024-thread block per batch, loops t=0..63. mem lives in LDS transposed
// [w][m] (stride 257, all accesses stride-1 or broadcast). Link in global,
// one coalesced row-per-wave pass per step (update + fwd + bwd fused).
// Scratch layouts are seg-major (consecutive lanes -> consecutive addresses).
__global__ __launch_bounds__(1024, 1) void k_memchain(const float* __restrict__ xi_all,
                                                      float* __restrict__ linkg,
                                                      float* __restrict__ rv_all) {
  const int b = blockIdx.x;
  const int tid = threadIdx.x;
  const int lane = tid & 63;
  const int wv = tid >> 6;       // 16 waves
  const int m8 = tid & 255;      // (m, seg) role: lanes -> consecutive m
  const int seg = tid >> 8;      // 0..3
  float* LNK = linkg + (size_t)b * (NCELL * NCELL);

  __shared__ __align__(16) float smemT[CSZ * SMT];
  __shared__ __align__(16) float sxi[472];
  __shared__ __align__(16) float srkn[NRD][64];
  __shared__ __align__(16) float swkn[64];
  __shared__ __align__(16) float sev[64];
  __shared__ __align__(16) float swvv[64];
  __shared__ __align__(16) float sscal[40];
  __shared__ __align__(16) float srw[NRD][256];
  __shared__ __align__(16) float sww[256];
  __shared__ __align__(16) float susage[256];
  __shared__ __align__(16) float sprec[256];
  __shared__ __align__(16) float ssim[NRD][256];
  __shared__ __align__(16) float sfwd[NRD][256];
  __shared__ __align__(16) float sbwd[NRD][264];
  __shared__ __align__(16) float sa[256];
  __shared__ __align__(16) float sc_[256];
  __shared__ float sb_[256];
  __shared__ int srank[256];
  __shared__ __align__(16) float scr[4][5 * 264];
  __shared__ float sred2[64];

  // ---- init ----
  for (int i = tid; i < CSZ * SMT; i += 1024) smemT[i] = 0.f;
  if (tid < 256) {
    sww[tid] = 0.f; susage[tid] = 0.f; sprec[tid] = 0.f;
    srw[0][tid] = 0.f; srw[1][tid] = 0.f; srw[2][tid] = 0.f; srw[3][tid] = 0.f;
  }
  for (int i = tid; i < (NCELL * NCELL) / 4; i += 1024)
    ((float4*)LNK)[i] = make_float4(0.f, 0.f, 0.f, 0.f);
  __syncthreads();

  for (int t = 0; t < TZ; ++t) {
    // ---- P0: load + parse xi ----
    if (tid < IFC) sxi[tid] = xi_all[((size_t)t * BZ + b) * 512 + tid];
    __syncthreads();
    if (wv < 4) {                        // read keys, per-head L2 norm
      float v = tanhf(sxi[wv * 64 + lane]);
      float s2 = v * v;
#pragma unroll
      for (int off = 32; off; off >>= 1) s2 += __shfl_xor(s2, off);
      srkn[wv][lane] = v / (sqrtf(s2) + DEL);
    } else if (wv == 4) {                // write key
      float v = tanhf(sxi[260 + lane]);
      float s2 = v * v;
#pragma unroll
      for (int off = 32; off; off >>= 1) s2 += __shfl_xor(s2, off);
      swkn[lane] = v / (sqrtf(s2) + DEL);
    } else if (wv == 5) {
      sev[lane] = sig_(sxi[325 + lane]);
    } else if (wv == 6) {
      swvv[lane] = tanhf(sxi[389 + lane]);
    } else if (wv == 7) {
      if (lane < 4) sscal[lane] = splus_(sxi[256 + lane]);                  // rs
      if (lane == 4) sscal[4] = splus_(sxi[324]);                           // ws
      if (lane >= 8 && lane < 12) sscal[lane] = sig_(sxi[453 + (lane - 8)]);// fg
      if (lane == 12) sscal[12] = sig_(sxi[457]);                           // ag
      if (lane == 13) sscal[13] = sig_(sxi[458]);                           // wg
      if (lane >= 16 && lane < 20) {                                        // rm softmax
        int r = lane - 16;
        float a = sxi[459 + r * 3], b2 = sxi[460 + r * 3], c2 = sxi[461 + r * 3];
        float mx3 = fmaxf(a, fmaxf(b2, c2));
        float ea = expf(a - mx3), eb = expf(b2 - mx3), ec = expf(c2 - mx3);
        float iv = 1.f / (ea + eb + ec);
        sscal[20 + r * 3 + 0] = ea * iv;
        sscal[20 + r * 3 + 1] = eb * iv;
        sscal[20 + r * 3 + 2] = ec * iv;
      }
    }
    __syncthreads();

    // ---- P1: usage update (old ww/rw) + write-content dot (old mem) ----
    float un_r = 0.f;
    if (tid < 256) {
      float wwo = sww[tid], uo = susage[tid];
      float u1 = uo + (1.f - uo) * wwo;
      float psi = 1.f;
#pragma unroll
      for (int r = 0; r < 4; ++r) psi *= 1.f - sscal[8 + r] * srw[r][tid];
      un_r = u1 * psi;
      susage[tid] = un_r;
    }
    {
      float dot = 0.f, nn = 0.f;
#pragma unroll 4
      for (int w = seg * 16; w < seg * 16 + 16; ++w) {
        float mv = smemT[w * SMT + m8];
        dot = fmaf(mv, swkn[w], dot);
        nn = fmaf(mv, mv, nn);
      }
      scr[seg][0 * 264 + m8] = dot;
      scr[seg][1 * 264 + m8] = nn;
    }
    __syncthreads();
    float e_r = 0.f, simv = 0.f;
    if (tid < 256) {
      float dot = scr[0][tid] + scr[1][tid] + scr[2][tid] + scr[3][tid];
      float nn = scr[0][264 + tid] + scr[1][264 + tid] + scr[2][264 + tid] + scr[3][264 + tid];
      simv = sscal[4] * dot / (sqrtf(nn) + DEL);
      float mx = simv;
#pragma unroll
      for (int off = 32; off; off >>= 1) mx = fmaxf(mx, __shfl_xor(mx, off));
      if (lane == 0) sred2[wv] = mx;
    }
    __syncthreads();
    if (tid < 256) {
      float mx = fmaxf(fmaxf(sred2[0], sred2[1]), fmaxf(sred2[2], sred2[3]));
      e_r = expf(simv - mx);
      float s = e_r;
#pragma unroll
      for (int off = 32; off; off >>= 1) s += __shfl_xor(s, off);
      if (lane == 0) sred2[8 + wv] = s;
    }
    __syncthreads();
    float wcw_r = 0.f;
    if (tid < 256) {
      float sm = sred2[8] + sred2[9] + sred2[10] + sred2[11];
      wcw_r = e_r / sm;
      sa[tid] = DEL + (1.f - DEL) * un_r;
    }
    __syncthreads();

    // ---- P2: allocation (stable rank + exclusive cumprod) ----
    {
      float um = sa[m8];
      int cnt = 0;
      for (int j2 = seg * 64; j2 < seg * 64 + 64; ++j2) {
        float uj = sa[j2];
        cnt += (uj < um || (uj == um && j2 < m8)) ? 1 : 0;
      }
      ((int*)scr[seg])[m8] = cnt;
    }
    __syncthreads();
    if (tid < 256) {
      int rank = ((int*)scr[0])[tid] + ((int*)scr[1])[tid] + ((int*)scr[2])[tid] + ((int*)scr[3])[tid];
      srank[tid] = rank;
      sb_[rank] = sa[tid];
    }
    __syncthreads();
    float inc = 0.f;
    if (tid < 256) {
      inc = sb_[tid];
#pragma unroll
      for (int off = 1; off < 64; off <<= 1) {
        float pp = __shfl_up(inc, off);
        if (lane >= off) inc *= pp;
      }
      if (lane == 63) sred2[16 + wv] = inc;
    }
    __syncthreads();
    if (tid < 256) {
      float pref = 1.f;
      for (int w2 = 0; w2 < wv; ++w2) pref *= sred2[16 + w2];
      float excl = __shfl_up(inc, 1);
      if (lane == 0) excl = 1.f;
      sc_[tid] = excl * pref;
    }
    __syncthreads();

    // ---- P3: write weighting + wsum ----
    if (tid < 256) {
      float alo = (1.f - sa[tid]) * sc_[srank[tid]];
      float wwn = sscal[13] * (sscal[12] * alo + (1.f - sscal[12]) * wcw_r);
      sww[tid] = wwn;
      float s = wwn;
#pragma unroll
      for (int off = 32; off; off >>= 1) s += __shfl_xor(s, off);
      if (lane == 0) sred2[24 + wv] = s;
    }
    __syncthreads();
    if (tid == 0) sscal[14] = sred2[24] + sred2[25] + sred2[26] + sred2[27];

    // ---- P4: memory erase/write + read-content sims (+ zero sbwd) ----
    {
      float wm = sww[m8];
      float nn = 0.f, d0 = 0.f, d1 = 0.f, d2 = 0.f, d3 = 0.f;
#pragma unroll 4
      for (int w = seg * 16; w < seg * 16 + 16; ++w) {
        float v = smemT[w * SMT + m8];
        v = v * (1.f - wm * sev[w]) + wm * swvv[w];
        smemT[w * SMT + m8] = v;
        nn = fmaf(v, v, nn);
        d0 = fmaf(v, srkn[0][w], d0);
        d1 = fmaf(v, srkn[1][w], d1);
        d2 = fmaf(v, srkn[2][w], d2);
        d3 = fmaf(v, srkn[3][w], d3);
      }
      scr[seg][0 * 264 + m8] = nn;
      scr[seg][1 * 264 + m8] = d0;
      scr[seg][2 * 264 + m8] = d1;
      scr[seg][3 * 264 + m8] = d2;
      scr[seg][4 * 264 + m8] = d3;
    }
    for (int i = tid; i < NRD * 264; i += 1024) ((float*)sbwd)[i] = 0.f;
    __syncthreads();
    float sv0 = 0.f, sv1 = 0.f, sv2 = 0.f, sv3 = 0.f;
    float e0 = 0.f, e1 = 0.f, e2 = 0.f, e3 = 0.f;
    if (tid < 256) {
      float nn = scr[0][tid] + scr[1][tid] + scr[2][tid] + scr[3][tid];
      float invn = 1.f / (sqrtf(nn) + DEL);
      sv0 = sscal[0] * (scr[0][264 + tid] + scr[1][264 + tid] + scr[2][264 + tid] + scr[3][264 + tid]) * invn;
      sv1 = sscal[1] * (scr[0][528 + tid] + scr[1][528 + tid] + scr[2][528 + tid] + scr[3][528 + tid]) * invn;
      sv2 = sscal[2] * (scr[0][792 + tid] + scr[1][792 + tid] + scr[2][792 + tid] + scr[3][792 + tid]) * invn;
      sv3 = sscal[3] * (scr[0][1056 + tid] + scr[1][1056 + tid] + scr[2][1056 + tid] + scr[3][1056 + tid]) * invn;
      float m0 = sv0, m1 = sv1, m2 = sv2, m3 = sv3;
#pragma unroll
      for (int off = 32; off; off >>= 1) {
        m0 = fmaxf(m0, __shfl_xor(m0, off));
        m1 = fmaxf(m1, __shfl_xor(m1, off));
        m2 = fmaxf(m2, __shfl_xor(m2, off));
        m3 = fmaxf(m3, __shfl_xor(m3, off));
      }
      if (lane == 0) {
        sred2[wv * 4 + 0] = m0; sred2[wv * 4 + 1] = m1;
        sred2[wv * 4 + 2] = m2; sred2[wv * 4 + 3] = m3;
      }
    }
    __syncthreads();
    if (tid < 256) {
      float m0 = fmaxf(fmaxf(sred2[0], sred2[4]), fmaxf(sred2[8], sred2[12]));
      float m1 = fmaxf(fmaxf(sred2[1], sred2[5]), fmaxf(sred2[9], sred2[13]));
      float m2 = fmaxf(fmaxf(sred2[2], sred2[6]), fmaxf(sred2[10], sred2[14]));
      float m3 = fmaxf(fmaxf(sred2[3], sred2[7]), fmaxf(sred2[11], sred2[15]));
      e0 = expf(sv0 - m0); e1 = expf(sv1 - m1); e2 = expf(sv2 - m2); e3 = expf(sv3 - m3);
      float s0 = e0, s1 = e1, s2 = e2, s3 = e3;
#pragma unroll
      for (int off = 32; off; off >>= 1) {
        s0 += __shfl_xor(s0, off); s1 += __shfl_xor(s1, off);
        s2 += __shfl_xor(s2, off); s3 += __shfl_xor(s3, off);
      }
      if (lane == 0) {
        sred2[32 + wv * 4 + 0] = s0; sred2[32 + wv * 4 + 1] = s1;
        sred2[32 + wv * 4 + 2] = s2; sred2[32 + wv * 4 + 3] = s3;
      }
    }
    __syncthreads();
    if (tid < 256) {
      float s0 = sred2[32] + sred2[36] + sred2[40] + sred2[44];
      float s1 = sred2[33] + sred2[37] + sred2[41] + sred2[45];
      float s2 = sred2[34] + sred2[38] + sred2[42] + sred2[46];
      float s3 = sred2[35] + sred2[39] + sred2[43] + sred2[47];
      ssim[0][tid] = e0 / s0; ssim[1][tid] = e1 / s1;
      ssim[2][tid] = e2 / s2; ssim[3][tid] = e3 / s3;
    }
    // no sync needed: ssim readers are after P5's sync.

    // ---- P5: link update + fwd + bwd, one coalesced row-per-wave pass ----
    {
      const float4 r0 = ((const float4*)srw[0])[lane];
      const float4 r1 = ((const float4*)srw[1])[lane];
      const float4 r2 = ((const float4*)srw[2])[lane];
      const float4 r3 = ((const float4*)srw[3])[lane];
      const float4 wc = ((const float4*)sww)[lane];
      const float4 pc = ((const float4*)sprec)[lane];
      const int n0 = lane * 4;
      float4 bp0 = make_float4(0.f, 0.f, 0.f, 0.f);
      float4 bp1 = make_float4(0.f, 0.f, 0.f, 0.f);
      float4 bp2 = make_float4(0.f, 0.f, 0.f, 0.f);
      float4 bp3 = make_float4(0.f, 0.f, 0.f, 0.f);
      for (int rr = 0; rr < 16; ++rr) {
        const int m = wv * 16 + rr;
        const float wm = sww[m];
        float4 lv = ((float4*)(LNK + (size_t)m * 256))[lane];
        lv.x = (1.f - wm - wc.x) * lv.x + wm * pc.x;
        lv.y = (1.f - wm - wc.y) * lv.y + wm * pc.y;
        lv.z = (1.f - wm - wc.z) * lv.z + wm * pc.z;
        lv.w = (1.f - wm - wc.w) * lv.w + wm * pc.w;
        if (m == n0 + 0) lv.x = 0.f;
        if (m == n0 + 1) lv.y = 0.f;
        if (m == n0 + 2) lv.z = 0.f;
        if (m == n0 + 3) lv.w = 0.f;
        ((float4*)(LNK + (size_t)m * 256))[lane] = lv;
        float f0 = lv.x * r0.x + lv.y * r0.y + lv.z * r0.z + lv.w * r0.w;
        float f1 = lv.x * r1.x + lv.y * r1.y + lv.z * r1.z + lv.w * r1.w;
        float f2 = lv.x * r2.x + lv.y * r2.y + lv.z * r2.z + lv.w * r2.w;
        float f3 = lv.x * r3.x + lv.y * r3.y + lv.z * r3.z + lv.w * r3.w;
#pragma unroll
        for (int off = 32; off; off >>= 1) {
          f0 += __shfl_xor(f0, off); f1 += __shfl_xor(f1, off);
          f2 += __shfl_xor(f2, off); f3 += __shfl_xor(f3, off);
        }
        if (lane == 0) {
          sfwd[0][m] = f0; sfwd[1][m] = f1; sfwd[2][m] = f2; sfwd[3][m] = f3;
        }
        const float s0 = srw[0][m], s1 = srw[1][m], s2 = srw[2][m], s3 = srw[3][m];
        bp0.x = fmaf(lv.x, s0, bp0.x); bp0.y = fmaf(lv.y, s0, bp0.y);
        bp0.z = fmaf(lv.z, s0, bp0.z); bp0.w = fmaf(lv.w, s0, bp0.w);
        bp1.x = fmaf(lv.x, s1, bp1.x); bp1.y = fmaf(lv.y, s1, bp1.y);
        bp1.z = fmaf(lv.z, s1, bp1.z); bp1.w = fmaf(lv.w, s1, bp1.w);
        bp2.x = fmaf(lv.x, s2, bp2.x); bp2.y = fmaf(lv.y, s2, bp2.y);
        bp2.z = fmaf(lv.z, s2, bp2.z); bp2.w = fmaf(lv.w, s2, bp2.w);
        bp3.x = fmaf(lv.x, s3, bp3.x); bp3.y = fmaf(lv.y, s3, bp3.y);
        bp3.z = fmaf(lv.z, s3, bp3.z); bp3.w = fmaf(lv.w, s3, bp3.w);
      }
      atomicAdd(&sbwd[0][n0 + 0], bp0.x); atomicAdd(&sbwd[0][n0 + 1], bp0.y);
      atomicAdd(&sbwd[0][n0 + 2], bp0.z); atomicAdd(&sbwd[0][n0 + 3], bp0.w);
      atomicAdd(&sbwd[1][n0 + 0], bp1.x); atomicAdd(&sbwd[1][n0 + 1], bp1.y);
      atomicAdd(&sbwd[1][n0 + 2], bp1.z); atomicAdd(&sbwd[1][n0 + 3], bp1.w);
      atomicAdd(&sbwd[2][n0 + 0], bp2.x); atomicAdd(&sbwd[2][n0 + 1], bp2.y);
      atomicAdd(&sbwd[2][n0 + 2], bp2.z); atomicAdd(&sbwd[2][n0 + 3], bp2.w);
      atomicAdd(&sbwd[3][n0 + 0], bp3.x); atomicAdd(&sbwd[3][n0 + 1], bp3.y);
      atomicAdd(&sbwd[3][n0 + 2], bp3.z); atomicAdd(&sbwd[3][n0 + 3], bp3.w);
    }
    __syncthreads();

    // ---- P7: rw update + precedence ----
    if (tid < 256) {
#pragma unroll
      for (int r = 0; r < 4; ++r) {
        float rwn = sscal[20 + r * 3 + 0] * sbwd[r][tid] +
                    sscal[20 + r * 3 + 1] * sfwd[r][tid] +
                    sscal[20 + r * 3 + 2] * ssim[r][tid];
        srw[r][tid] = rwn;
      }
      sprec[tid] = (1.f - sscal[14]) * sprec[tid] + sww[tid];
    }
    __syncthreads();

    // ---- P8: read vectors: rv[r][w] = sum_m rw[r][m] * mem[m][w] ----
    {
      const int r = tid >> 8, sg = (tid >> 6) & 3, w = lane;
      float acc = 0.f;
#pragma unroll 4
      for (int m2 = sg * 64; m2 < sg * 64 + 64; ++m2)
        acc = fmaf(srw[r][m2], smemT[w * SMT + m2], acc);
      scr[sg][r * 64 + w] = acc;
    }
    __syncthreads();
    if (tid < 256)
      rv_all[((size_t)t * BZ + b) * 256 + tid] =
          scr[0][tid] + scr[1][tid] + scr[2][tid] + scr[3][tid];
    __syncthreads();
  }
}

// ---------------------------------------------------------------- final y GEMM
__global__ __launch_bounds__(256) void k_y(const float* __restrict__ out_all,
                                           const float* __restrict__ rv_all,
                                           const float* __restrict__ WmemT,
                                           const float* __restrict__ bmem,
                                           float* __restrict__ y) {
  const int lane = threadIdx.x, ty = threadIdx.y;
  const int o = blockIdx.x * 64 + lane;
  const int tb0 = blockIdx.y * 16;
  __shared__ float sin_[16][768];
  const int tid = ty * 64 + lane;
  for (int idx = tid; idx < 16 * 768; idx += 256) {
    int row = idx / 768, k = idx % 768;
    int tb = tb0 + row;
    sin_[row][k] = (k < 512) ? out_all[(size_t)tb * HID + k]
                             : rv_all[(size_t)tb * 256 + (k - 512)];
  }
  __syncthreads();
  float acc[4] = {0.f, 0.f, 0.f, 0.f};
  for (int k = 0; k < 768; ++k) {
    float wv = WmemT[(size_t)k * 256 + o];
#pragma unroll
    for (int i = 0; i < 4; ++i) acc[i] = fmaf(wv, sin_[ty * 4 + i][k], acc[i]);
  }
  float bo = bmem[o];
#pragma unroll
  for (int i = 0; i < 4; ++i) {
    int tb = tb0 + ty * 4 + i;
    int tt = tb >> 4, bb = tb & 15;
    y[((size_t)bb * TZ + tt) * 256 + o] = acc[i] + bo;
  }
}

extern "C" void kernel_launch(void* const* d_in, const int* in_sizes, int n_in,
                              void* d_out, int out_size, void* d_ws, size_t ws_size,
                              hipStream_t stream) {
  (void)in_sizes; (void)n_in; (void)out_size; (void)ws_size;
  const float* x    = (const float*)d_in[0];
  const float* Wih0 = (const float*)d_in[1];
  const float* bih0 = (const float*)d_in[2];
  const float* Whh0 = (const float*)d_in[3];
  const float* bhh0 = (const float*)d_in[4];
  const float* Wih1 = (const float*)d_in[5];
  const float* bih1 = (const float*)d_in[6];
  const float* Whh1 = (const float*)d_in[7];
  const float* bhh1 = (const float*)d_in[8];
  const float* Wout = (const float*)d_in[9];
  const float* bout = (const float*)d_in[10];
  const float* Wif  = (const float*)d_in[11];
  const float* bif  = (const float*)d_in[12];
  const float* Wmem = (const float*)d_in[13];
  const float* bmem = (const float*)d_in[14];
  float* y = (float*)d_out;

  float* p = (float*)d_ws;
  auto take = [&](size_t n) { float* q = p; p += n; return q; };
  float* Wih0T   = take((size_t)256 * 2048);
  float* Whh0T   = take((size_t)512 * 2048);
  float* Wih1T   = take((size_t)512 * 2048);
  float* Whh1T   = take((size_t)512 * 2048);
  float* WoutT   = take((size_t)512 * 512);
  float* WifT    = take((size_t)512 * 512);
  float* WmemT   = take((size_t)768 * 256);
  float* xpart   = take((size_t)TZ * BZ * G4H);
  float* h1_all  = take((size_t)TZ * BZ * HID);
  float* out_all = take((size_t)TZ * BZ * HID);
  float* xi_all  = take((size_t)TZ * BZ * 512);
  float* rv_all  = take((size_t)TZ * BZ * 256);
  float* linkg   = take((size_t)BZ * NCELL * NCELL);
  float* zstart  = p;
  float* h0      = take((size_t)2 * BZ * HID);
  float* c0      = take((size_t)BZ * HID);
  float* h1      = take((size_t)2 * BZ * HID);
  float* c1      = take((size_t)BZ * HID);
  size_t zbytes = (size_t)((char*)p - (char*)zstart);

  hipMemsetAsync(zstart, 0, zbytes, stream);

  dim3 tb32(32, 8);
  hipLaunchKernelGGL(k_transpose, dim3(8, 64), tb32, 0, stream, Wih0, Wih0T, 2048, 512, 256, 2048);
  hipLaunchKernelGGL(k_transpose, dim3(16, 64), tb32, 0, stream, Whh0, Whh0T, 2048, 512, 512, 2048);
  hipLaunchKernelGGL(k_transpose, dim3(16, 64), tb32, 0, stream, Wih1, Wih1T, 2048, 512, 512, 2048);
  hipLaunchKernelGGL(k_transpose, dim3(16, 64), tb32, 0, stream, Whh1, Whh1T, 2048, 512, 512, 2048);
  hipLaunchKernelGGL(k_transpose, dim3(16, 16), tb32, 0, stream, Wout, WoutT, 512, 512, 512, 512);
  hipLaunchKernelGGL(k_transpose, dim3(16, 15), tb32, 0, stream, Wif, WifT, 471, 512, 512, 512);
  hipLaunchKernelGGL(k_transpose, dim3(24, 8), tb32, 0, stream, Wmem, WmemT, 256, 768, 768, 256);

  hipLaunchKernelGGL(k_xpart, dim3(32, 64), dim3(64, 4), 0, stream, x, Wih0T, bih0, bhh0, xpart);

  for (int ph = 0; ph <= TZ; ++ph)
    hipLaunchKernelGGL(k_lstm_step, dim3(256), dim3(64, 4), 0, stream,
                       xpart, Whh0T, Wih1T, Whh1T, bih1, bhh1,
                       h0, c0, h1, c1, h1_all, ph);

  hipLaunchKernelGGL(k_xiout, dim3(16, 64), dim3(64, 4), 0, stream,
                     h1_all, WoutT, WifT, bout, bif, out_all, xi_all);

  hipLaunchKernelGGL(k_memchain, dim3(16), dim3(1024), 0, stream,
                     xi_all, linkg, rv_all);

  hipLaunchKernelGGL(k_y, dim3(4, 64), dim3(64, 4), 0, stream, out_all, rv_all, WmemT, bmem, y);
}